// Round 5
// baseline (238.677 us; speedup 1.0000x reference)
//
#include <hip/hip_runtime.h>

typedef __attribute__((ext_vector_type(8))) short short8;
typedef __attribute__((ext_vector_type(4))) short short4v;
typedef __attribute__((ext_vector_type(4))) float f32x4;
typedef _Float16 half8 __attribute__((ext_vector_type(8)));

#define ASYNC16(g, l) __builtin_amdgcn_global_load_lds( \
    (__attribute__((address_space(1))) void*)(g), \
    (__attribute__((address_space(3))) void*)(l), 16, 0, 0)

__device__ __forceinline__ short f2bf(float f) {
  union { float f; unsigned u; } v; v.f = f;
  unsigned r = v.u + 0x7fffu + ((v.u >> 16) & 1u);
  return (short)(r >> 16);
}

__device__ __forceinline__ short f2h(float f) {  // f32 -> f16 bits (RTNE)
  _Float16 h = (_Float16)f;
  return __builtin_bit_cast(short, h);
}

__device__ __forceinline__ unsigned pkh2(float a, float b) {  // 2xf16 packed, RTZ
  return __builtin_bit_cast(unsigned, __builtin_amdgcn_cvt_pkrtz(a, b));
}

__device__ __forceinline__ f32x4 fzero4() {
  f32x4 z; z[0] = 0.f; z[1] = 0.f; z[2] = 0.f; z[3] = 0.f; return z;
}

// barrier that does NOT drain vmcnt: in-flight DMA stages / reg prefetches survive.
__device__ __forceinline__ void wg_barrier() {
  asm volatile("s_waitcnt lgkmcnt(0)\n\ts_barrier" ::: "memory");
}

// counted waits for out_gemm's 2-deep pipeline (proven R2 win).
__device__ __forceinline__ void wait6_barrier() {
  asm volatile("s_waitcnt vmcnt(6)\n\ts_barrier" ::: "memory");
}
__device__ __forceinline__ void wait0_barrier() {
  asm volatile("s_waitcnt vmcnt(0)\n\ts_barrier" ::: "memory");
}

// ---------- fp32 -> bf16 conversion of x1, x2, Wq, Wk, Wv, Wo ----------
__global__ __launch_bounds__(256) void cvt_all(
    const float* __restrict__ x1, const float* __restrict__ x2,
    const float* __restrict__ wq, const float* __restrict__ wk,
    const float* __restrict__ wv, const float* __restrict__ wo,
    short* __restrict__ dst) {
  long e = ((long)blockIdx.x * 256 + threadIdx.x) * 4;
  const float* src; long loc;
  if (e < 4194304L)       { src = x1; loc = e; }
  else if (e < 12582912L) { src = x2; loc = e - 4194304L; }
  else if (e < 13631488L) { src = wq; loc = e - 12582912L; }
  else if (e < 14680064L) { src = wk; loc = e - 13631488L; }
  else if (e < 15728640L) { src = wv; loc = e - 14680064L; }
  else                    { src = wo; loc = e - 15728640L; }
  float4 v = *(const float4*)(src + loc);
  short4v o;
  o[0] = f2bf(v.x); o[1] = f2bf(v.y); o[2] = f2bf(v.z); o[3] = f2bf(v.w);
  *(short4v*)(dst + e) = o;
}

// ---------- fused Q/K/V projection GEMM ----------
// R0 structure byte-exact (best measured: 67.9 us, reproduced R4: 67.8). BK=32,
// 2 barriers/step, 5 blocks/CU; inter-block wave overlap hides the drains (m114).
// Structural edits (dbuf depth-1, counted 2-deep, BK=64) all regressed — do not touch.
__global__ __launch_bounds__(256) void proj(
    const short* __restrict__ xb1, const short* __restrict__ xb2,
    const short* __restrict__ wqp, const short* __restrict__ wkp, const short* __restrict__ wvp,
    const float* __restrict__ bq, const float* __restrict__ bk, const float* __restrict__ bv,
    short* __restrict__ qb, short* __restrict__ kb, short* __restrict__ vb) {
  __shared__ short smem[16384];
  short* As = smem;
  short* Bs = smem + 4096;
  const int tid = threadIdx.x, w = tid >> 6, lane = tid & 63;
  const int quad = lane >> 4, col = lane & 15;
  const int waveM = (w >> 1) * 64, waveN = (w & 1) * 64;
  const int my = blockIdx.x, bn = blockIdx.y * 128;
  const short* A; const short* W; const float* bias; int mode, bm;
  if (my < 32)      { A = xb1; W = wqp; bias = bq; mode = 0; bm = my * 128; }
  else if (my < 96) { A = xb2; W = wkp; bias = bk; mode = 1; bm = (my - 32) * 128; }
  else              { A = xb2; W = wvp; bias = bv; mode = 2; bm = (my - 96) * 128; }

  f32x4 acc[4][4];
  for (int mi = 0; mi < 4; ++mi)
    for (int ni = 0; ni < 4; ++ni)
      acc[mi][ni] = fzero4();

  const int srow = w * 16 + (lane >> 2), scol = (lane & 3) * 8;
  const short* ga = A + (size_t)(bm + srow) * 1024 + scol;
  const short* gb = W + (size_t)(bn + srow) * 1024 + scol;
  short* lA = As + w * 512;
  short* lB = Bs + w * 512;

  for (int kk = 0; kk < 1024; kk += 32) {
    __syncthreads();
    ASYNC16(ga + kk,         lA);
    ASYNC16(ga + kk + 65536, lA + 2048);
    ASYNC16(gb + kk,         lB);
    ASYNC16(gb + kk + 65536, lB + 2048);
    __syncthreads();
    short8 af[4], bf[4];
    for (int mi = 0; mi < 4; ++mi)
      af[mi] = *(const short8*)(As + (waveM + mi * 16 + col) * 32 + quad * 8);
    for (int ni = 0; ni < 4; ++ni)
      bf[ni] = *(const short8*)(Bs + (waveN + ni * 16 + col) * 32 + quad * 8);
    for (int mi = 0; mi < 4; ++mi)
      for (int ni = 0; ni < 4; ++ni)
        acc[mi][ni] = __builtin_amdgcn_mfma_f32_16x16x32_bf16(af[mi], bf[ni], acc[mi][ni], 0, 0, 0);
  }

  __syncthreads();
  for (int ni = 0; ni < 4; ++ni) {
    int nn = waveN + ni * 16 + col;
    float bvl = bias[bn + nn];
    for (int mi = 0; mi < 4; ++mi) {
      int m0 = waveM + mi * 16 + quad * 4;
      for (int r = 0; r < 4; ++r) {
        int m = m0 + r;
        float val = acc[mi][ni][r] + bvl;
        short sv;
        if (mode == 0)      sv = f2bf(val * 0.18033688011112042f);  // log2(e)/8
        else if (mode == 1) sv = f2bf(val);
        else                sv = f2h(val);                           // V in f16
        smem[m * 128 + (nn ^ ((m & 15) << 3))] = sv;
      }
    }
  }
  __syncthreads();
  if (mode < 2) {
    const int S = (mode == 0) ? 1024 : 2048;
    short* outp = (mode == 0) ? qb : kb;
    const int bb = bm / S, s0 = bm & (S - 1), h0 = bn >> 6;
    for (int it = 0; it < 8; ++it) {
      int f = (it * 256 + tid) * 8;
      int hh = f >> 13, rem = f & 8191, m = rem >> 6, d = rem & 63;
      int nn = hh * 64 + d;
      short8 val = *(const short8*)&smem[m * 128 + (nn ^ ((m & 15) << 3))];
      *(short8*)(outp + ((((size_t)(bb * 16 + h0 + hh)) * S + s0 + m) * 64 + d)) = val;
    }
  } else {
    // v tiled transposed f16: [bh][kt64][d][kv'], kv' = (kv%16)*4 + kv/16
    const int bb = bm >> 11, s0 = bm & 2047, kt0 = s0 >> 6, h0 = bn >> 6;
    for (int it = 0; it < 8; ++it) {
      int f = (it * 256 + tid) * 8;
      int hh = f >> 13, rem = f & 8191, ktl = rem >> 12, r3 = rem & 4095;
      int d = r3 >> 6, kvp0 = r3 & 63;
      int nn = hh * 64 + d;
      short8 val;
      for (int j = 0; j < 8; ++j) {
        int kvp = kvp0 + j;
        int kv = ((kvp & 3) << 4) | (kvp >> 2);
        int m = ktl * 64 + kv;
        val[j] = smem[m * 128 + (nn ^ ((m & 15) << 3))];
      }
      *(short8*)(vb + ((((size_t)(bb * 16 + h0 + hh)) * 32 + (kt0 + ktl)) * 4096) + d * 64 + kvp0) = val;
    }
  }
}

// ---------- output GEMM: out[4096,1024] fp32 = ob @ Wo^T + bo ----------
// 128x64 tiles, BK=64, grid (16 n, 32 m) = 512 blocks.
// R2's 2-deep counted-vmcnt pipeline (proven win) — unchanged.
__global__ __launch_bounds__(256) void out_gemm(
    const short* __restrict__ A, const short* __restrict__ W,
    const float* __restrict__ bias, float* __restrict__ out) {
  __shared__ short smem[24576];  // buf b at b*12288: A0 | A1 (4096 each) | B0 | B1 (2048 each)
  const int tid = threadIdx.x, w = tid >> 6, lane = tid & 63;
  const int quad = lane >> 4, col = lane & 15;
  const int waveM = (w >> 1) * 64, waveN = (w & 1) * 32;
  const int bn = blockIdx.x * 64, bm = blockIdx.y * 128;

  f32x4 acc[4][2];
  for (int mi = 0; mi < 4; ++mi)
    for (int ni = 0; ni < 2; ++ni)
      acc[mi][ni] = fzero4();

  const int arow = w * 16 + (lane >> 2), ac = (lane & 3) * 8;
  const short* ga = A + (size_t)(bm + arow) * 1024 + ac;
  const short* gb = W + (size_t)(bn + (tid >> 2)) * 1024 + (tid & 3) * 8;

  auto stage = [&](int b, int kk) {
    short* base = smem + b * 12288;
    short* lA0 = base + w * 512;
    short* lA1 = base + 4096 + w * 512;
    short* lB0 = base + 8192 + w * 512;
    short* lB1 = base + 10240 + w * 512;
    ASYNC16(ga + kk,              lA0);
    ASYNC16(ga + kk + 65536,      lA0 + 2048);
    ASYNC16(ga + kk + 32,         lA1);
    ASYNC16(ga + kk + 32 + 65536, lA1 + 2048);
    ASYNC16(gb + kk,              lB0);
    ASYNC16(gb + kk + 32,         lB1);
  };
  auto compute = [&](int b) {
    const short* base = smem + b * 12288;
    for (int kh = 0; kh < 2; ++kh) {
      const short* Ash = base + kh * 4096;
      const short* Bsh = base + 8192 + kh * 2048;
      short8 af[4], bf[2];
      for (int mi = 0; mi < 4; ++mi)
        af[mi] = *(const short8*)(Ash + (waveM + mi * 16 + col) * 32 + quad * 8);
      for (int ni = 0; ni < 2; ++ni)
        bf[ni] = *(const short8*)(Bsh + (waveN + ni * 16 + col) * 32 + quad * 8);
      for (int mi = 0; mi < 4; ++mi)
        for (int ni = 0; ni < 2; ++ni)
          acc[mi][ni] = __builtin_amdgcn_mfma_f32_16x16x32_bf16(af[mi], bf[ni], acc[mi][ni], 0, 0, 0);
    }
  };

  // prologue: tiles 0,1 in flight (12 loads)
  stage(0, 0);
  stage(1, 64);
  for (int it = 0; it < 14; ++it) {
    wait6_barrier();               // tile it landed (oldest 6 of 12)
    compute(it & 1);
    wg_barrier();                  // reads retired -> safe to re-stage
    stage(it & 1, (it + 2) * 64);
  }
  wait6_barrier();                 // tile 14 landed
  compute(0);
  wait0_barrier();                 // tile 15 landed
  compute(1);

  for (int ni = 0; ni < 2; ++ni) {
    int n = bn + waveN + ni * 16 + col;
    float bvl = bias[n];
    for (int mi = 0; mi < 4; ++mi) {
      int m0 = bm + waveM + mi * 16 + quad * 4;
      for (int r = 0; r < 4; ++r)
        out[(size_t)(m0 + r) * 1024 + n] = acc[mi][ni][r] + bvl;
    }
  }
}

// ---------- flash attention: no-max softmax, Q pre-scaled, f16 P/V, MFMA row-sums ----------
// EXACT R2 bytes: NO setprio. This kernel is 4-wave lockstep (wg_barrier per tile,
// all waves same role) with 2 blocks/CU — the m190 regime where setprio HURTS
// (it starves the co-resident block's staging waves; R2-vs-R4 rest delta ~19 us).
__global__ __launch_bounds__(256, 2) void attn(
    const short* __restrict__ Q, const short* __restrict__ K,
    const short* __restrict__ V, short* __restrict__ O) {
  __shared__ short Ks[128 * 72];
  __shared__ short Vs[80 * 136];   // f16 [d][chunk*64 + kv']; row 64 = ones (lsum), 65..79 = 0
  __shared__ short Ps[128 * 136];  // f16 [q][chunk*64 + kv']
  const int tid = threadIdx.x, w = tid >> 6, lane = tid & 63;
  const int quad = lane >> 4, col = lane & 15;
  const int bh = blockIdx.x, qt = blockIdx.y;
  const int b = bh >> 4, h = bh & 15;
  const int qbase = w * 32;

  const short* qp = Q + ((size_t)bh * 1024 + qt * 128) * 64;
  const short* kp = K + (size_t)bh * 131072;
  const short* vp = V + (size_t)bh * 131072;

  short8 aq[2][2];
  for (int mi = 0; mi < 2; ++mi) {
    const short* qr = qp + (qbase + mi * 16 + col) * 64 + quad * 8;
    aq[mi][0] = *(const short8*)qr;
    aq[mi][1] = *(const short8*)(qr + 32);
  }

  f32x4 oa[2][5];
  for (int mi = 0; mi < 2; ++mi)
    for (int ni = 0; ni < 5; ++ni)
      oa[mi][ni] = fzero4();

  // ones row (f16 1.0 = 0x3C00) at d=64; zero d=65..79
  for (int i = tid; i < 16 * 136; i += 256)
    Vs[64 * 136 + i] = (i < 136) ? (short)0x3C00 : (short)0;

  const int krow = lane + (w >> 1) * 64, kch = (w & 1) * 32;
  const int vd = lane, vch = w & 1, vkh = (w >> 1) * 32;

  short8 kpre[4], vpre[4];
  {
    const short* kg = kp + krow * 64 + kch;
    const short* vg = vp + vch * 4096 + vd * 64 + vkh;
    for (int i = 0; i < 4; ++i) kpre[i] = *(const short8*)(kg + i * 8);
    for (int i = 0; i < 4; ++i) vpre[i] = *(const short8*)(vg + i * 8);
  }

  for (int kt = 0; kt < 16; ++kt) {
    wg_barrier();  // prior tile's LDS reads done (lgkm only; prefetch vmcnt in flight)
    for (int i = 0; i < 4; ++i)
      *(short8*)&Ks[krow * 72 + kch + i * 8] = kpre[i];
    for (int i = 0; i < 4; ++i)
      *(short8*)&Vs[vd * 136 + vch * 64 + vkh + i * 8] = vpre[i];
    {
      int ktn = (kt < 15) ? kt + 1 : kt;
      const short* kg = kp + ktn * 8192 + krow * 64 + kch;
      const short* vg = vp + (2 * ktn + vch) * 4096 + vd * 64 + vkh;
      for (int i = 0; i < 4; ++i) kpre[i] = *(const short8*)(kg + i * 8);
      for (int i = 0; i < 4; ++i) vpre[i] = *(const short8*)(vg + i * 8);
    }
    wg_barrier();

    // S = Q K^T (Q pre-scaled so S is already log2-domain); K-frags read once, shared by both mi
    f32x4 sf[2][8];
    for (int nk = 0; nk < 8; ++nk) {
      short8 bk0 = *(const short8*)&Ks[(nk * 16 + col) * 72 + quad * 8];
      short8 bk1 = *(const short8*)&Ks[(nk * 16 + col) * 72 + 32 + quad * 8];
      f32x4 z0 = fzero4(), z1 = fzero4();
      z0 = __builtin_amdgcn_mfma_f32_16x16x32_bf16(aq[0][0], bk0, z0, 0, 0, 0);
      z0 = __builtin_amdgcn_mfma_f32_16x16x32_bf16(aq[0][1], bk1, z0, 0, 0, 0);
      z1 = __builtin_amdgcn_mfma_f32_16x16x32_bf16(aq[1][0], bk0, z1, 0, 0, 0);
      z1 = __builtin_amdgcn_mfma_f32_16x16x32_bf16(aq[1][1], bk1, z1, 0, 0, 0);
      sf[0][nk] = z0;
      sf[1][nk] = z1;
    }

    // p = 2^s (no max-sub: scores bounded, shift-invariant); pack f16 pairs, write P
    for (int mi = 0; mi < 2; ++mi)
      for (int nk = 0; nk < 8; ++nk)
        for (int r = 0; r < 4; ++r)
          sf[mi][nk][r] = __builtin_amdgcn_exp2f(sf[mi][nk][r]);
    for (int mi = 0; mi < 2; ++mi)
      for (int r = 0; r < 4; ++r) {
        int row = qbase + mi * 16 + quad * 4 + r;
        uint2 d0, d1;
        d0.x = pkh2(sf[mi][0][r], sf[mi][1][r]);
        d0.y = pkh2(sf[mi][2][r], sf[mi][3][r]);
        d1.x = pkh2(sf[mi][4][r], sf[mi][5][r]);
        d1.y = pkh2(sf[mi][6][r], sf[mi][7][r]);
        *(uint2*)&Ps[row * 136 + col * 4]      = d0;
        *(uint2*)&Ps[row * 136 + 64 + col * 4] = d1;
      }
    // no barrier: each wave reads only its own Ps rows

    // O += P V (f16); ni=4 tile hits the ones-row -> oa[mi][4] lane col0 = row-sum
    for (int ks = 0; ks < 4; ++ks) {
      int koff = ks * 32 + quad * 8;
      half8 ap0 = *(const half8*)&Ps[(qbase + col) * 136 + koff];
      half8 ap1 = *(const half8*)&Ps[(qbase + 16 + col) * 136 + koff];
      for (int ni = 0; ni < 5; ++ni) {
        half8 bv = *(const half8*)&Vs[(ni * 16 + col) * 136 + koff];
        oa[0][ni] = __builtin_amdgcn_mfma_f32_16x16x32_f16(ap0, bv, oa[0][ni], 0, 0, 0);
        oa[1][ni] = __builtin_amdgcn_mfma_f32_16x16x32_f16(ap1, bv, oa[1][ni], 0, 0, 0);
      }
    }
  }

  // normalize: lsum lives in oa[mi][4][r] of each quad's col-0 lane; broadcast within quad
  float inv[2][4];
  for (int mi = 0; mi < 2; ++mi)
    for (int r = 0; r < 4; ++r) {
      float s = __shfl(oa[mi][4][r], lane & 48);
      inv[mi][r] = 1.f / s;
    }
  __syncthreads();
  for (int mi = 0; mi < 2; ++mi)
    for (int ni = 0; ni < 4; ++ni)
      for (int r = 0; r < 4; ++r)
        Ps[(qbase + mi * 16 + quad * 4 + r) * 64 + ni * 16 + col] = f2bf(oa[mi][ni][r] * inv[mi][r]);
  __syncthreads();
  for (int it = 0; it < 4; ++it) {
    int f = (it * 256 + tid) * 8;  // over [128 q][64 d]
    int q = f >> 6, d = f & 63;
    short8 val = *(const short8*)&Ps[q * 64 + d];
    *(short8*)(O + ((size_t)(b * 1024 + qt * 128 + q)) * 1024 + h * 64 + d) = val;
  }
}

// ---------- launcher ----------
extern "C" void kernel_launch(void* const* d_in, const int* in_sizes, int n_in,
                              void* d_out, int out_size, void* d_ws, size_t ws_size,
                              hipStream_t stream) {
  const float* x1 = (const float*)d_in[0];
  const float* x2 = (const float*)d_in[1];
  const float* Wq = (const float*)d_in[2];
  const float* bq = (const float*)d_in[3];
  const float* Wk = (const float*)d_in[4];
  const float* bk = (const float*)d_in[5];
  const float* Wv = (const float*)d_in[6];
  const float* bv = (const float*)d_in[7];
  const float* Wo = (const float*)d_in[8];
  const float* bo = (const float*)d_in[9];

  char* ws = (char*)d_ws;
  short* xb1 = (short*)(ws + 0);         // x1 bf16, 8 MB
  short* xb2 = (short*)(ws + 8388608);   // x2 bf16, 16 MB
  short* wqb = (short*)(ws + 25165824);  // Wq bf16, 2 MB
  short* wkb = (short*)(ws + 27262976);
  short* wvb = (short*)(ws + 29360128);
  short* wob = (short*)(ws + 31457280);
  short* qb  = (short*)(ws + 33554432);  // q [bh][1024][64] bf16 (pre-scaled), 8 MB
  short* kb  = (short*)(ws + 41943040);  // k [bh][2048][64] bf16, 16 MB
  short* vb  = (short*)(ws + 58720256);  // v tiled f16 [bh][32][64][64], 16 MB
  short* ob  = (short*)(ws + 75497472);  // attn out [4096][1024] bf16, 8 MB

  cvt_all<<<16384, 256, 0, stream>>>(x1, x2, Wq, Wk, Wv, Wo, (short*)ws);
  proj<<<dim3(160, 8), 256, 0, stream>>>(xb1, xb2, wqb, wkb, wvb, bq, bk, bv, qb, kb, vb);
  attn<<<dim3(64, 8), 256, 0, stream>>>(qb, kb, vb, ob);
  out_gemm<<<dim3(16, 32), 256, 0, stream>>>(ob, wob, bo, (float*)d_out);
}

// Round 7
// 236.964 us; speedup vs baseline: 1.0072x; 1.0072x over previous
//
#include <hip/hip_runtime.h>

typedef __attribute__((ext_vector_type(8))) short short8;
typedef __attribute__((ext_vector_type(4))) short short4v;
typedef __attribute__((ext_vector_type(4))) float f32x4;
typedef _Float16 half8 __attribute__((ext_vector_type(8)));

#define ASYNC16(g, l) __builtin_amdgcn_global_load_lds( \
    (__attribute__((address_space(1))) void*)(g), \
    (__attribute__((address_space(3))) void*)(l), 16, 0, 0)

__device__ __forceinline__ short f2bf(float f) {
  union { float f; unsigned u; } v; v.f = f;
  unsigned r = v.u + 0x7fffu + ((v.u >> 16) & 1u);
  return (short)(r >> 16);
}

__device__ __forceinline__ short f2h(float f) {  // f32 -> f16 bits (RTNE)
  _Float16 h = (_Float16)f;
  return __builtin_bit_cast(short, h);
}

__device__ __forceinline__ unsigned pkh2(float a, float b) {  // 2xf16 packed, RTZ
  return __builtin_bit_cast(unsigned, __builtin_amdgcn_cvt_pkrtz(a, b));
}

__device__ __forceinline__ f32x4 fzero4() {
  f32x4 z; z[0] = 0.f; z[1] = 0.f; z[2] = 0.f; z[3] = 0.f; return z;
}

// barrier that does NOT drain vmcnt: in-flight DMA stages / reg prefetches survive.
__device__ __forceinline__ void wg_barrier() {
  asm volatile("s_waitcnt lgkmcnt(0)\n\ts_barrier" ::: "memory");
}

// counted waits (T4): oldest loads landed + all waves synced. Never vmcnt(0) mid-loop.
__device__ __forceinline__ void wait4_barrier() {
  asm volatile("s_waitcnt vmcnt(4) lgkmcnt(0)\n\ts_barrier" ::: "memory");
}
__device__ __forceinline__ void wait6_barrier() {
  asm volatile("s_waitcnt vmcnt(6)\n\ts_barrier" ::: "memory");
}
__device__ __forceinline__ void wait0_barrier() {
  asm volatile("s_waitcnt vmcnt(0)\n\ts_barrier" ::: "memory");
}

// ---------- fp32 -> bf16 conversion of x1, x2, Wq, Wk, Wv, Wo ----------
__global__ __launch_bounds__(256) void cvt_all(
    const float* __restrict__ x1, const float* __restrict__ x2,
    const float* __restrict__ wq, const float* __restrict__ wk,
    const float* __restrict__ wv, const float* __restrict__ wo,
    short* __restrict__ dst) {
  long e = ((long)blockIdx.x * 256 + threadIdx.x) * 4;
  const float* src; long loc;
  if (e < 4194304L)       { src = x1; loc = e; }
  else if (e < 12582912L) { src = x2; loc = e - 4194304L; }
  else if (e < 13631488L) { src = wq; loc = e - 12582912L; }
  else if (e < 14680064L) { src = wk; loc = e - 13631488L; }
  else if (e < 15728640L) { src = wv; loc = e - 14680064L; }
  else                    { src = wo; loc = e - 15728640L; }
  float4 v = *(const float4*)(src + loc);
  short4v o;
  o[0] = f2bf(v.x); o[1] = f2bf(v.y); o[2] = f2bf(v.z); o[3] = f2bf(v.w);
  *(short4v*)(dst + e) = o;
}

// ---------- fused Q/K/V projection GEMM ----------
// R6 STRUCTURE (typo fixed): 3-buffer counted pipeline + bank-conflict-free swizzle.
//  - LDS 48KB = 3 x (A 8KB | B 8KB); stage(kt+2) never touches a buffer that
//    kt or kt+1 reads -> race-free with ONE barrier + vmcnt(4) per K-tile.
//  - Old layout was an 8-way bank conflict per ds_read_b128 (bank group
//    (4*(col&1)+quad) takes 2 values over a 16-lane phase; SQ_LDS_BANK_CONFLICT 5.6M).
//    Swizzle: physical chunk c at row R holds logical chunk c ^ ((R>>1)&3);
//    read fetches chunk quad ^ ((col>>1)&3) -> all 8 bank groups, 2 lanes each (free).
//    Linear gload_lds dest + inverse-swizzled GLOBAL source col (rule #21).
//  - Epilogue reuses smem[0..16383] after a barrier.
__global__ __launch_bounds__(256) void proj(
    const short* __restrict__ xb1, const short* __restrict__ xb2,
    const short* __restrict__ wqp, const short* __restrict__ wkp, const short* __restrict__ wvp,
    const float* __restrict__ bq, const float* __restrict__ bk, const float* __restrict__ bv,
    short* __restrict__ qb, short* __restrict__ kb, short* __restrict__ vb) {
  __shared__ short smem[24576];  // 3 bufs x 8192 shorts (A:4096 | B:4096)
  const int tid = threadIdx.x, w = tid >> 6, lane = tid & 63;
  const int quad = lane >> 4, col = lane & 15;
  const int waveM = (w >> 1) * 64, waveN = (w & 1) * 64;
  const int my = blockIdx.x, bn = blockIdx.y * 128;
  const short* A; const short* W; const float* bias; int mode, bm;
  if (my < 32)      { A = xb1; W = wqp; bias = bq; mode = 0; bm = my * 128; }
  else if (my < 96) { A = xb2; W = wkp; bias = bk; mode = 1; bm = (my - 32) * 128; }
  else              { A = xb2; W = wvp; bias = bv; mode = 2; bm = (my - 96) * 128; }

  f32x4 acc[4][4];
  for (int mi = 0; mi < 4; ++mi)
    for (int ni = 0; ni < 4; ++ni)
      acc[mi][ni] = fzero4();

  // staging: lane l fills LDS slot (row = l>>2, chunk = l&3); under the swizzle that
  // slot holds logical chunk (l&3)^((l>>3)&3)  [bits 1-2 of row = (l>>3)&3].
  const int srow = w * 16 + (lane >> 2);
  const int scol = ((lane & 3) ^ ((lane >> 3) & 3)) * 8;
  const short* ga = A + (size_t)(bm + srow) * 1024 + scol;
  const short* gb = W + (size_t)(bn + srow) * 1024 + scol;
  // read-side swizzle: fragment row bits 1-2 = col bits 1-2 (waveM/mi*16 are mult of 16)
  const int csw = (col >> 1) & 3;

  auto stage = [&](int kt) {
    short* base = smem + (kt % 3) * 8192;
    short* lA = base + w * 512;
    short* lB = base + 4096 + w * 512;
    const int kk = kt * 32;
    ASYNC16(ga + kk,         lA);
    ASYNC16(ga + kk + 65536, lA + 2048);
    ASYNC16(gb + kk,         lB);
    ASYNC16(gb + kk + 65536, lB + 2048);
  };
  auto compute = [&](int kt) {
    const short* As_ = smem + (kt % 3) * 8192;
    const short* Bs_ = As_ + 4096;
    short8 af[4], bf[4];
    for (int mi = 0; mi < 4; ++mi)
      af[mi] = *(const short8*)(As_ + (waveM + mi * 16 + col) * 32 + (quad ^ csw) * 8);
    for (int ni = 0; ni < 4; ++ni)
      bf[ni] = *(const short8*)(Bs_ + (waveN + ni * 16 + col) * 32 + (quad ^ csw) * 8);
    for (int mi = 0; mi < 4; ++mi)
      for (int ni = 0; ni < 4; ++ni)
        acc[mi][ni] = __builtin_amdgcn_mfma_f32_16x16x32_bf16(af[mi], bf[ni], acc[mi][ni], 0, 0, 0);
  };

  // prologue: K-tiles 0,1 in flight (8 loads)
  stage(0);
  stage(1);
  for (int kt = 0; kt < 31; ++kt) {
    wait4_barrier();            // my kt loads retired + all waves' reads of buf (kt-1)%3 done
    if (kt < 30) stage(kt + 2); // writes buf (kt+2)%3 = (kt-1)%3: reads of it done pre-barrier
    compute(kt);
  }
  wait0_barrier();              // tile 31 landed
  compute(31);
  __syncthreads();              // all waves done reading bufs before epilogue overwrites

  for (int ni = 0; ni < 4; ++ni) {
    int nn = waveN + ni * 16 + col;
    float bvl = bias[bn + nn];
    for (int mi = 0; mi < 4; ++mi) {
      int m0 = waveM + mi * 16 + quad * 4;
      for (int r = 0; r < 4; ++r) {
        int m = m0 + r;
        float val = acc[mi][ni][r] + bvl;
        short sv;
        if (mode == 0)      sv = f2bf(val * 0.18033688011112042f);  // log2(e)/8
        else if (mode == 1) sv = f2bf(val);
        else                sv = f2h(val);                           // V in f16
        smem[m * 128 + (nn ^ ((m & 15) << 3))] = sv;
      }
    }
  }
  __syncthreads();
  if (mode < 2) {
    const int S = (mode == 0) ? 1024 : 2048;
    short* outp = (mode == 0) ? qb : kb;
    const int bb = bm / S, s0 = bm & (S - 1), h0 = bn >> 6;
    for (int it = 0; it < 8; ++it) {
      int f = (it * 256 + tid) * 8;
      int hh = f >> 13, rem = f & 8191, m = rem >> 6, d = rem & 63;
      int nn = hh * 64 + d;
      short8 val = *(const short8*)&smem[m * 128 + (nn ^ ((m & 15) << 3))];
      *(short8*)(outp + ((((size_t)(bb * 16 + h0 + hh)) * S + s0 + m) * 64 + d)) = val;
    }
  } else {
    // v tiled transposed f16: [bh][kt64][d][kv'], kv' = (kv%16)*4 + kv/16
    const int bb = bm >> 11, s0 = bm & 2047, kt0 = s0 >> 6, h0 = bn >> 6;
    for (int it = 0; it < 8; ++it) {
      int f = (it * 256 + tid) * 8;
      int hh = f >> 13, rem = f & 8191, ktl = rem >> 12, r3 = rem & 4095;
      int d = r3 >> 6, kvp0 = r3 & 63;
      int nn = hh * 64 + d;
      short8 val;
      for (int j = 0; j < 8; ++j) {
        int kvp = kvp0 + j;
        int kv = ((kvp & 3) << 4) | (kvp >> 2);
        int m = ktl * 64 + kv;
        val[j] = smem[m * 128 + (nn ^ ((m & 15) << 3))];
      }
      *(short8*)(vb + ((((size_t)(bb * 16 + h0 + hh)) * 32 + (kt0 + ktl)) * 4096) + d * 64 + kvp0) = val;
    }
  }
}

// ---------- output GEMM: out[4096,1024] fp32 = ob @ Wo^T + bo ----------
// 128x64 tiles, BK=64, grid (16 n, 32 m) = 512 blocks.
// R2's 2-deep counted-vmcnt pipeline (proven win) — unchanged.
__global__ __launch_bounds__(256) void out_gemm(
    const short* __restrict__ A, const short* __restrict__ W,
    const float* __restrict__ bias, float* __restrict__ out) {
  __shared__ short smem[24576];  // buf b at b*12288: A0 | A1 (4096 each) | B0 | B1 (2048 each)
  const int tid = threadIdx.x, w = tid >> 6, lane = tid & 63;
  const int quad = lane >> 4, col = lane & 15;
  const int waveM = (w >> 1) * 64, waveN = (w & 1) * 32;
  const int bn = blockIdx.x * 64, bm = blockIdx.y * 128;

  f32x4 acc[4][2];
  for (int mi = 0; mi < 4; ++mi)
    for (int ni = 0; ni < 2; ++ni)
      acc[mi][ni] = fzero4();

  const int arow = w * 16 + (lane >> 2), ac = (lane & 3) * 8;
  const short* ga = A + (size_t)(bm + arow) * 1024 + ac;
  const short* gb = W + (size_t)(bn + (tid >> 2)) * 1024 + (tid & 3) * 8;

  auto stage = [&](int b, int kk) {
    short* base = smem + b * 12288;
    short* lA0 = base + w * 512;
    short* lA1 = base + 4096 + w * 512;
    short* lB0 = base + 8192 + w * 512;
    short* lB1 = base + 10240 + w * 512;
    ASYNC16(ga + kk,              lA0);
    ASYNC16(ga + kk + 65536,      lA0 + 2048);
    ASYNC16(ga + kk + 32,         lA1);
    ASYNC16(ga + kk + 32 + 65536, lA1 + 2048);
    ASYNC16(gb + kk,              lB0);
    ASYNC16(gb + kk + 32,         lB1);
  };
  auto compute = [&](int b) {
    const short* base = smem + b * 12288;
    for (int kh = 0; kh < 2; ++kh) {
      const short* Ash = base + kh * 4096;
      const short* Bsh = base + 8192 + kh * 2048;
      short8 af[4], bf[2];
      for (int mi = 0; mi < 4; ++mi)
        af[mi] = *(const short8*)(Ash + (waveM + mi * 16 + col) * 32 + quad * 8);
      for (int ni = 0; ni < 2; ++ni)
        bf[ni] = *(const short8*)(Bsh + (waveN + ni * 16 + col) * 32 + quad * 8);
      for (int mi = 0; mi < 4; ++mi)
        for (int ni = 0; ni < 2; ++ni)
          acc[mi][ni] = __builtin_amdgcn_mfma_f32_16x16x32_bf16(af[mi], bf[ni], acc[mi][ni], 0, 0, 0);
    }
  };

  // prologue: tiles 0,1 in flight (12 loads)
  stage(0, 0);
  stage(1, 64);
  for (int it = 0; it < 14; ++it) {
    wait6_barrier();               // tile it landed (oldest 6 of 12)
    compute(it & 1);
    wg_barrier();                  // reads retired -> safe to re-stage
    stage(it & 1, (it + 2) * 64);
  }
  wait6_barrier();                 // tile 14 landed
  compute(0);
  wait0_barrier();                 // tile 15 landed
  compute(1);

  for (int ni = 0; ni < 2; ++ni) {
    int n = bn + waveN + ni * 16 + col;
    float bvl = bias[n];
    for (int mi = 0; mi < 4; ++mi) {
      int m0 = bm + waveM + mi * 16 + quad * 4;
      for (int r = 0; r < 4; ++r)
        out[(size_t)(m0 + r) * 1024 + n] = acc[mi][ni][r] + bvl;
    }
  }
}

// ---------- flash attention: no-max softmax, Q pre-scaled, f16 P/V, MFMA row-sums ----------
// R2/R5 bytes (no setprio): R5 A/B showed setprio was noise, keep the simpler form.
__global__ __launch_bounds__(256, 2) void attn(
    const short* __restrict__ Q, const short* __restrict__ K,
    const short* __restrict__ V, short* __restrict__ O) {
  __shared__ short Ks[128 * 72];
  __shared__ short Vs[80 * 136];   // f16 [d][chunk*64 + kv']; row 64 = ones (lsum), 65..79 = 0
  __shared__ short Ps[128 * 136];  // f16 [q][chunk*64 + kv']
  const int tid = threadIdx.x, w = tid >> 6, lane = tid & 63;
  const int quad = lane >> 4, col = lane & 15;
  const int bh = blockIdx.x, qt = blockIdx.y;
  const int b = bh >> 4, h = bh & 15;
  const int qbase = w * 32;

  const short* qp = Q + ((size_t)bh * 1024 + qt * 128) * 64;
  const short* kp = K + (size_t)bh * 131072;
  const short* vp = V + (size_t)bh * 131072;

  short8 aq[2][2];
  for (int mi = 0; mi < 2; ++mi) {
    const short* qr = qp + (qbase + mi * 16 + col) * 64 + quad * 8;
    aq[mi][0] = *(const short8*)qr;
    aq[mi][1] = *(const short8*)(qr + 32);
  }

  f32x4 oa[2][5];
  for (int mi = 0; mi < 2; ++mi)
    for (int ni = 0; ni < 5; ++ni)
      oa[mi][ni] = fzero4();

  // ones row (f16 1.0 = 0x3C00) at d=64; zero d=65..79
  for (int i = tid; i < 16 * 136; i += 256)
    Vs[64 * 136 + i] = (i < 136) ? (short)0x3C00 : (short)0;

  const int krow = lane + (w >> 1) * 64, kch = (w & 1) * 32;
  const int vd = lane, vch = w & 1, vkh = (w >> 1) * 32;

  short8 kpre[4], vpre[4];
  {
    const short* kg = kp + krow * 64 + kch;
    const short* vg = vp + vch * 4096 + vd * 64 + vkh;
    for (int i = 0; i < 4; ++i) kpre[i] = *(const short8*)(kg + i * 8);
    for (int i = 0; i < 4; ++i) vpre[i] = *(const short8*)(vg + i * 8);
  }

  for (int kt = 0; kt < 16; ++kt) {
    wg_barrier();  // prior tile's LDS reads done (lgkm only; prefetch vmcnt in flight)
    for (int i = 0; i < 4; ++i)
      *(short8*)&Ks[krow * 72 + kch + i * 8] = kpre[i];
    for (int i = 0; i < 4; ++i)
      *(short8*)&Vs[vd * 136 + vch * 64 + vkh + i * 8] = vpre[i];
    {
      int ktn = (kt < 15) ? kt + 1 : kt;
      const short* kg = kp + ktn * 8192 + krow * 64 + kch;
      const short* vg = vp + (2 * ktn + vch) * 4096 + vd * 64 + vkh;
      for (int i = 0; i < 4; ++i) kpre[i] = *(const short8*)(kg + i * 8);
      for (int i = 0; i < 4; ++i) vpre[i] = *(const short8*)(vg + i * 8);
    }
    wg_barrier();

    // S = Q K^T (Q pre-scaled so S is already log2-domain); K-frags read once, shared by both mi
    f32x4 sf[2][8];
    for (int nk = 0; nk < 8; ++nk) {
      short8 bk0 = *(const short8*)&Ks[(nk * 16 + col) * 72 + quad * 8];
      short8 bk1 = *(const short8*)&Ks[(nk * 16 + col) * 72 + 32 + quad * 8];
      f32x4 z0 = fzero4(), z1 = fzero4();
      z0 = __builtin_amdgcn_mfma_f32_16x16x32_bf16(aq[0][0], bk0, z0, 0, 0, 0);
      z0 = __builtin_amdgcn_mfma_f32_16x16x32_bf16(aq[0][1], bk1, z0, 0, 0, 0);
      z1 = __builtin_amdgcn_mfma_f32_16x16x32_bf16(aq[1][0], bk0, z1, 0, 0, 0);
      z1 = __builtin_amdgcn_mfma_f32_16x16x32_bf16(aq[1][1], bk1, z1, 0, 0, 0);
      sf[0][nk] = z0;
      sf[1][nk] = z1;
    }

    // p = 2^s (no max-sub: scores bounded, shift-invariant); pack f16 pairs, write P
    for (int mi = 0; mi < 2; ++mi)
      for (int nk = 0; nk < 8; ++nk)
        for (int r = 0; r < 4; ++r)
          sf[mi][nk][r] = __builtin_amdgcn_exp2f(sf[mi][nk][r]);
    for (int mi = 0; mi < 2; ++mi)
      for (int r = 0; r < 4; ++r) {
        int row = qbase + mi * 16 + quad * 4 + r;
        uint2 d0, d1;
        d0.x = pkh2(sf[mi][0][r], sf[mi][1][r]);
        d0.y = pkh2(sf[mi][2][r], sf[mi][3][r]);
        d1.x = pkh2(sf[mi][4][r], sf[mi][5][r]);
        d1.y = pkh2(sf[mi][6][r], sf[mi][7][r]);
        *(uint2*)&Ps[row * 136 + col * 4]      = d0;
        *(uint2*)&Ps[row * 136 + 64 + col * 4] = d1;
      }
    // no barrier: each wave reads only its own Ps rows

    // O += P V (f16); ni=4 tile hits the ones-row -> oa[mi][4] lane col0 = row-sum
    for (int ks = 0; ks < 4; ++ks) {
      int koff = ks * 32 + quad * 8;
      half8 ap0 = *(const half8*)&Ps[(qbase + col) * 136 + koff];
      half8 ap1 = *(const half8*)&Ps[(qbase + 16 + col) * 136 + koff];
      for (int ni = 0; ni < 5; ++ni) {
        half8 bv = *(const half8*)&Vs[(ni * 16 + col) * 136 + koff];
        oa[0][ni] = __builtin_amdgcn_mfma_f32_16x16x32_f16(ap0, bv, oa[0][ni], 0, 0, 0);
        oa[1][ni] = __builtin_amdgcn_mfma_f32_16x16x32_f16(ap1, bv, oa[1][ni], 0, 0, 0);
      }
    }
  }

  // normalize: lsum lives in oa[mi][4][r] of each quad's col-0 lane; broadcast within quad
  float inv[2][4];
  for (int mi = 0; mi < 2; ++mi)
    for (int r = 0; r < 4; ++r) {
      float s = __shfl(oa[mi][4][r], lane & 48);
      inv[mi][r] = 1.f / s;
    }
  __syncthreads();
  for (int mi = 0; mi < 2; ++mi)
    for (int ni = 0; ni < 4; ++ni)
      for (int r = 0; r < 4; ++r)
        Ps[(qbase + mi * 16 + quad * 4 + r) * 64 + ni * 16 + col] = f2bf(oa[mi][ni][r] * inv[mi][r]);
  __syncthreads();
  for (int it = 0; it < 4; ++it) {
    int f = (it * 256 + tid) * 8;  // over [128 q][64 d]
    int q = f >> 6, d = f & 63;
    short8 val = *(const short8*)&Ps[q * 64 + d];
    *(short8*)(O + ((size_t)(b * 1024 + qt * 128 + q)) * 1024 + h * 64 + d) = val;
  }
}

// ---------- launcher ----------
extern "C" void kernel_launch(void* const* d_in, const int* in_sizes, int n_in,
                              void* d_out, int out_size, void* d_ws, size_t ws_size,
                              hipStream_t stream) {
  const float* x1 = (const float*)d_in[0];
  const float* x2 = (const float*)d_in[1];
  const float* Wq = (const float*)d_in[2];
  const float* bq = (const float*)d_in[3];
  const float* Wk = (const float*)d_in[4];
  const float* bk = (const float*)d_in[5];
  const float* Wv = (const float*)d_in[6];
  const float* bv = (const float*)d_in[7];
  const float* Wo = (const float*)d_in[8];
  const float* bo = (const float*)d_in[9];

  char* ws = (char*)d_ws;
  short* xb1 = (short*)(ws + 0);         // x1 bf16, 8 MB
  short* xb2 = (short*)(ws + 8388608);   // x2 bf16, 16 MB
  short* wqb = (short*)(ws + 25165824);  // Wq bf16, 2 MB
  short* wkb = (short*)(ws + 27262976);
  short* wvb = (short*)(ws + 29360128);
  short* wob = (short*)(ws + 31457280);
  short* qb  = (short*)(ws + 33554432);  // q [bh][1024][64] bf16 (pre-scaled), 8 MB
  short* kb  = (short*)(ws + 41943040);  // k [bh][2048][64] bf16, 16 MB
  short* vb  = (short*)(ws + 58720256);  // v tiled f16 [bh][32][64][64], 16 MB
  short* ob  = (short*)(ws + 75497472);  // attn out [4096][1024] bf16, 8 MB

  cvt_all<<<16384, 256, 0, stream>>>(x1, x2, Wq, Wk, Wv, Wo, (short*)ws);
  proj<<<dim3(160, 8), 256, 0, stream>>>(xb1, xb2, wqb, wkb, wvb, bq, bk, bv, qb, kb, vb);
  attn<<<dim3(64, 8), 256, 0, stream>>>(qb, kb, vb, ob);
  out_gemm<<<dim3(16, 32), 256, 0, stream>>>(ob, wob, bo, (float*)d_out);
}

// Round 8
// 235.115 us; speedup vs baseline: 1.0152x; 1.0079x over previous
//
#include <hip/hip_runtime.h>

typedef __attribute__((ext_vector_type(8))) short short8;
typedef __attribute__((ext_vector_type(4))) short short4v;
typedef __attribute__((ext_vector_type(4))) float f32x4;
typedef _Float16 half8 __attribute__((ext_vector_type(8)));

#define ASYNC16(g, l) __builtin_amdgcn_global_load_lds( \
    (__attribute__((address_space(1))) void*)(g), \
    (__attribute__((address_space(3))) void*)(l), 16, 0, 0)

__device__ __forceinline__ short f2bf(float f) {
  union { float f; unsigned u; } v; v.f = f;
  unsigned r = v.u + 0x7fffu + ((v.u >> 16) & 1u);
  return (short)(r >> 16);
}

__device__ __forceinline__ short f2h(float f) {  // f32 -> f16 bits (RTNE)
  _Float16 h = (_Float16)f;
  return __builtin_bit_cast(short, h);
}

__device__ __forceinline__ unsigned pkh2(float a, float b) {  // 2xf16 packed, RTZ
  return __builtin_bit_cast(unsigned, __builtin_amdgcn_cvt_pkrtz(a, b));
}

__device__ __forceinline__ f32x4 fzero4() {
  f32x4 z; z[0] = 0.f; z[1] = 0.f; z[2] = 0.f; z[3] = 0.f; return z;
}

// barrier that does NOT drain vmcnt: in-flight DMA stages / reg prefetches survive.
__device__ __forceinline__ void wg_barrier() {
  asm volatile("s_waitcnt lgkmcnt(0)\n\ts_barrier" ::: "memory");
}

// counted waits (T4): oldest loads landed + all waves synced. Never vmcnt(0) mid-loop.
__device__ __forceinline__ void wait4_barrier() {
  asm volatile("s_waitcnt vmcnt(4) lgkmcnt(0)\n\ts_barrier" ::: "memory");
}
__device__ __forceinline__ void wait6_barrier() {
  asm volatile("s_waitcnt vmcnt(6)\n\ts_barrier" ::: "memory");
}
__device__ __forceinline__ void wait0_barrier() {
  asm volatile("s_waitcnt vmcnt(0)\n\ts_barrier" ::: "memory");
}

// ---------- fp32 -> bf16 conversion of x1, x2, Wq, Wk, Wv, Wo ----------
__global__ __launch_bounds__(256) void cvt_all(
    const float* __restrict__ x1, const float* __restrict__ x2,
    const float* __restrict__ wq, const float* __restrict__ wk,
    const float* __restrict__ wv, const float* __restrict__ wo,
    short* __restrict__ dst) {
  long e = ((long)blockIdx.x * 256 + threadIdx.x) * 4;
  const float* src; long loc;
  if (e < 4194304L)       { src = x1; loc = e; }
  else if (e < 12582912L) { src = x2; loc = e - 4194304L; }
  else if (e < 13631488L) { src = wq; loc = e - 12582912L; }
  else if (e < 14680064L) { src = wk; loc = e - 13631488L; }
  else if (e < 15728640L) { src = wv; loc = e - 14680064L; }
  else                    { src = wo; loc = e - 15728640L; }
  float4 v = *(const float4*)(src + loc);
  short4v o;
  o[0] = f2bf(v.x); o[1] = f2bf(v.y); o[2] = f2bf(v.z); o[3] = f2bf(v.w);
  *(short4v*)(dst + e) = o;
}

// ---------- fused Q/K/V projection GEMM ----------
// R7 structure (3-buffer counted pipeline + bank-swizzle, conflicts 5.6M->360K)
// with the K-loop UNROLLED BY 3: buffer indices are literals, fragment LDS
// offsets hoisted -> kills the `% 3` + per-iter address chains that R7's
// counters exposed as VALUBusy 40% (vs 17% in the 2-buffer version).
__global__ __launch_bounds__(256) void proj(
    const short* __restrict__ xb1, const short* __restrict__ xb2,
    const short* __restrict__ wqp, const short* __restrict__ wkp, const short* __restrict__ wvp,
    const float* __restrict__ bq, const float* __restrict__ bk, const float* __restrict__ bv,
    short* __restrict__ qb, short* __restrict__ kb, short* __restrict__ vb) {
  __shared__ short smem[24576];  // 3 bufs x 8192 shorts (A:4096 | B:4096)
  const int tid = threadIdx.x, w = tid >> 6, lane = tid & 63;
  const int quad = lane >> 4, col = lane & 15;
  const int waveM = (w >> 1) * 64, waveN = (w & 1) * 64;
  const int my = blockIdx.x, bn = blockIdx.y * 128;
  const short* A; const short* W; const float* bias; int mode, bm;
  if (my < 32)      { A = xb1; W = wqp; bias = bq; mode = 0; bm = my * 128; }
  else if (my < 96) { A = xb2; W = wkp; bias = bk; mode = 1; bm = (my - 32) * 128; }
  else              { A = xb2; W = wvp; bias = bv; mode = 2; bm = (my - 96) * 128; }

  f32x4 acc[4][4];
  for (int mi = 0; mi < 4; ++mi)
    for (int ni = 0; ni < 4; ++ni)
      acc[mi][ni] = fzero4();

  // staging: lane l fills LDS slot (row = l>>2, chunk = l&3); under the swizzle that
  // slot holds logical chunk (l&3)^((l>>3)&3)  [bits 1-2 of row = (l>>3)&3].
  const int srow = w * 16 + (lane >> 2);
  const int scol = ((lane & 3) ^ ((lane >> 3) & 3)) * 8;
  const short* ga = A + (size_t)(bm + srow) * 1024 + scol;
  const short* gb = W + (size_t)(bn + srow) * 1024 + scol;
  // read-side swizzle: fragment row bits 1-2 = col bits 1-2 (waveM/mi*16 are mult of 16)
  const int csw = (col >> 1) & 3;

  // hoisted fragment offsets (loop-invariant)
  int aoff[4], boff[4];
  for (int mi = 0; mi < 4; ++mi)
    aoff[mi] = (waveM + mi * 16 + col) * 32 + (quad ^ csw) * 8;
  for (int ni = 0; ni < 4; ++ni)
    boff[ni] = 4096 + (waveN + ni * 16 + col) * 32 + (quad ^ csw) * 8;
  short* const stA = smem + w * 512;
  short* const stB = smem + 4096 + w * 512;

#define PSTAGE(B, KK) do {                       \
    ASYNC16(ga + (KK),         stA + (B) * 8192); \
    ASYNC16(ga + (KK) + 65536, stA + (B) * 8192 + 2048); \
    ASYNC16(gb + (KK),         stB + (B) * 8192); \
    ASYNC16(gb + (KK) + 65536, stB + (B) * 8192 + 2048); \
  } while (0)

#define PCOMPUTE(B, KK) do {                     \
    const short* base_ = smem + (B) * 8192;      \
    short8 af[4], bf[4];                         \
    for (int mi = 0; mi < 4; ++mi)               \
      af[mi] = *(const short8*)(base_ + aoff[mi]); \
    for (int ni = 0; ni < 4; ++ni)               \
      bf[ni] = *(const short8*)(base_ + boff[ni]); \
    for (int mi = 0; mi < 4; ++mi)               \
      for (int ni = 0; ni < 4; ++ni)             \
        acc[mi][ni] = __builtin_amdgcn_mfma_f32_16x16x32_bf16(af[mi], bf[ni], acc[mi][ni], 0, 0, 0); \
  } while (0)

  // prologue: K-tiles 0,1 in flight (8 loads)
  PSTAGE(0, 0);
  PSTAGE(1, 32);
  // main: 10 macro-iters x 3 kt (all buffer indices literal), kt=30,31 peeled
#pragma unroll 1
  for (int t = 0; t < 10; ++t) {
    const int kk = t * 96;
    wait4_barrier(); PSTAGE(2, kk + 64);  PCOMPUTE(0, kk);
    wait4_barrier(); PSTAGE(0, kk + 96);  PCOMPUTE(1, kk + 32);
    wait4_barrier(); PSTAGE(1, kk + 128); PCOMPUTE(2, kk + 64);
  }
  wait4_barrier();  PCOMPUTE(0, 960);   // kt=30 (no stage: kt+2 would be 32)
  wait0_barrier();  PCOMPUTE(1, 992);   // kt=31
  __syncthreads();                      // all reads done before epilogue overwrites
#undef PSTAGE
#undef PCOMPUTE

  for (int ni = 0; ni < 4; ++ni) {
    int nn = waveN + ni * 16 + col;
    float bvl = bias[bn + nn];
    for (int mi = 0; mi < 4; ++mi) {
      int m0 = waveM + mi * 16 + quad * 4;
      for (int r = 0; r < 4; ++r) {
        int m = m0 + r;
        float val = acc[mi][ni][r] + bvl;
        short sv;
        if (mode == 0)      sv = f2bf(val * 0.18033688011112042f);  // log2(e)/8
        else if (mode == 1) sv = f2bf(val);
        else                sv = f2h(val);                           // V in f16
        smem[m * 128 + (nn ^ ((m & 15) << 3))] = sv;
      }
    }
  }
  __syncthreads();
  if (mode < 2) {
    const int S = (mode == 0) ? 1024 : 2048;
    short* outp = (mode == 0) ? qb : kb;
    const int bb = bm / S, s0 = bm & (S - 1), h0 = bn >> 6;
    for (int it = 0; it < 8; ++it) {
      int f = (it * 256 + tid) * 8;
      int hh = f >> 13, rem = f & 8191, m = rem >> 6, d = rem & 63;
      int nn = hh * 64 + d;
      short8 val = *(const short8*)&smem[m * 128 + (nn ^ ((m & 15) << 3))];
      *(short8*)(outp + ((((size_t)(bb * 16 + h0 + hh)) * S + s0 + m) * 64 + d)) = val;
    }
  } else {
    // v tiled transposed f16: [bh][kt64][d][kv'], kv' = (kv%16)*4 + kv/16
    const int bb = bm >> 11, s0 = bm & 2047, kt0 = s0 >> 6, h0 = bn >> 6;
    for (int it = 0; it < 8; ++it) {
      int f = (it * 256 + tid) * 8;
      int hh = f >> 13, rem = f & 8191, ktl = rem >> 12, r3 = rem & 4095;
      int d = r3 >> 6, kvp0 = r3 & 63;
      int nn = hh * 64 + d;
      short8 val;
      for (int j = 0; j < 8; ++j) {
        int kvp = kvp0 + j;
        int kv = ((kvp & 3) << 4) | (kvp >> 2);
        int m = ktl * 64 + kv;
        val[j] = smem[m * 128 + (nn ^ ((m & 15) << 3))];
      }
      *(short8*)(vb + ((((size_t)(bb * 16 + h0 + hh)) * 32 + (kt0 + ktl)) * 4096) + d * 64 + kvp0) = val;
    }
  }
}

// ---------- output GEMM: out[4096,1024] fp32 = ob @ Wo^T + bo ----------
// 128x64 tiles, BK=64, grid (16 n, 32 m) = 512 blocks.
// R2's 2-deep counted-vmcnt pipeline (proven win) — unchanged.
__global__ __launch_bounds__(256) void out_gemm(
    const short* __restrict__ A, const short* __restrict__ W,
    const float* __restrict__ bias, float* __restrict__ out) {
  __shared__ short smem[24576];  // buf b at b*12288: A0 | A1 (4096 each) | B0 | B1 (2048 each)
  const int tid = threadIdx.x, w = tid >> 6, lane = tid & 63;
  const int quad = lane >> 4, col = lane & 15;
  const int waveM = (w >> 1) * 64, waveN = (w & 1) * 32;
  const int bn = blockIdx.x * 64, bm = blockIdx.y * 128;

  f32x4 acc[4][2];
  for (int mi = 0; mi < 4; ++mi)
    for (int ni = 0; ni < 2; ++ni)
      acc[mi][ni] = fzero4();

  const int arow = w * 16 + (lane >> 2), ac = (lane & 3) * 8;
  const short* ga = A + (size_t)(bm + arow) * 1024 + ac;
  const short* gb = W + (size_t)(bn + (tid >> 2)) * 1024 + (tid & 3) * 8;

  auto stage = [&](int b, int kk) {
    short* base = smem + b * 12288;
    short* lA0 = base + w * 512;
    short* lA1 = base + 4096 + w * 512;
    short* lB0 = base + 8192 + w * 512;
    short* lB1 = base + 10240 + w * 512;
    ASYNC16(ga + kk,              lA0);
    ASYNC16(ga + kk + 65536,      lA0 + 2048);
    ASYNC16(ga + kk + 32,         lA1);
    ASYNC16(ga + kk + 32 + 65536, lA1 + 2048);
    ASYNC16(gb + kk,              lB0);
    ASYNC16(gb + kk + 32,         lB1);
  };
  auto compute = [&](int b) {
    const short* base = smem + b * 12288;
    for (int kh = 0; kh < 2; ++kh) {
      const short* Ash = base + kh * 4096;
      const short* Bsh = base + 8192 + kh * 2048;
      short8 af[4], bf[2];
      for (int mi = 0; mi < 4; ++mi)
        af[mi] = *(const short8*)(Ash + (waveM + mi * 16 + col) * 32 + quad * 8);
      for (int ni = 0; ni < 2; ++ni)
        bf[ni] = *(const short8*)(Bsh + (waveN + ni * 16 + col) * 32 + quad * 8);
      for (int mi = 0; mi < 4; ++mi)
        for (int ni = 0; ni < 2; ++ni)
          acc[mi][ni] = __builtin_amdgcn_mfma_f32_16x16x32_bf16(af[mi], bf[ni], acc[mi][ni], 0, 0, 0);
    }
  };

  // prologue: tiles 0,1 in flight (12 loads)
  stage(0, 0);
  stage(1, 64);
  for (int it = 0; it < 14; ++it) {
    wait6_barrier();               // tile it landed (oldest 6 of 12)
    compute(it & 1);
    wg_barrier();                  // reads retired -> safe to re-stage
    stage(it & 1, (it + 2) * 64);
  }
  wait6_barrier();                 // tile 14 landed
  compute(0);
  wait0_barrier();                 // tile 15 landed
  compute(1);

  for (int ni = 0; ni < 2; ++ni) {
    int n = bn + waveN + ni * 16 + col;
    float bvl = bias[n];
    for (int mi = 0; mi < 4; ++mi) {
      int m0 = bm + waveM + mi * 16 + quad * 4;
      for (int r = 0; r < 4; ++r)
        out[(size_t)(m0 + r) * 1024 + n] = acc[mi][ni][r] + bvl;
    }
  }
}

// ---------- flash attention: no-max softmax, Q pre-scaled, f16 P/V, MFMA row-sums ----------
// R2/R5 bytes (no setprio) — unchanged this round.
__global__ __launch_bounds__(256, 2) void attn(
    const short* __restrict__ Q, const short* __restrict__ K,
    const short* __restrict__ V, short* __restrict__ O) {
  __shared__ short Ks[128 * 72];
  __shared__ short Vs[80 * 136];   // f16 [d][chunk*64 + kv']; row 64 = ones (lsum), 65..79 = 0
  __shared__ short Ps[128 * 136];  // f16 [q][chunk*64 + kv']
  const int tid = threadIdx.x, w = tid >> 6, lane = tid & 63;
  const int quad = lane >> 4, col = lane & 15;
  const int bh = blockIdx.x, qt = blockIdx.y;
  const int b = bh >> 4, h = bh & 15;
  const int qbase = w * 32;

  const short* qp = Q + ((size_t)bh * 1024 + qt * 128) * 64;
  const short* kp = K + (size_t)bh * 131072;
  const short* vp = V + (size_t)bh * 131072;

  short8 aq[2][2];
  for (int mi = 0; mi < 2; ++mi) {
    const short* qr = qp + (qbase + mi * 16 + col) * 64 + quad * 8;
    aq[mi][0] = *(const short8*)qr;
    aq[mi][1] = *(const short8*)(qr + 32);
  }

  f32x4 oa[2][5];
  for (int mi = 0; mi < 2; ++mi)
    for (int ni = 0; ni < 5; ++ni)
      oa[mi][ni] = fzero4();

  // ones row (f16 1.0 = 0x3C00) at d=64; zero d=65..79
  for (int i = tid; i < 16 * 136; i += 256)
    Vs[64 * 136 + i] = (i < 136) ? (short)0x3C00 : (short)0;

  const int krow = lane + (w >> 1) * 64, kch = (w & 1) * 32;
  const int vd = lane, vch = w & 1, vkh = (w >> 1) * 32;

  short8 kpre[4], vpre[4];
  {
    const short* kg = kp + krow * 64 + kch;
    const short* vg = vp + vch * 4096 + vd * 64 + vkh;
    for (int i = 0; i < 4; ++i) kpre[i] = *(const short8*)(kg + i * 8);
    for (int i = 0; i < 4; ++i) vpre[i] = *(const short8*)(vg + i * 8);
  }

  for (int kt = 0; kt < 16; ++kt) {
    wg_barrier();  // prior tile's LDS reads done (lgkm only; prefetch vmcnt in flight)
    for (int i = 0; i < 4; ++i)
      *(short8*)&Ks[krow * 72 + kch + i * 8] = kpre[i];
    for (int i = 0; i < 4; ++i)
      *(short8*)&Vs[vd * 136 + vch * 64 + vkh + i * 8] = vpre[i];
    {
      int ktn = (kt < 15) ? kt + 1 : kt;
      const short* kg = kp + ktn * 8192 + krow * 64 + kch;
      const short* vg = vp + (2 * ktn + vch) * 4096 + vd * 64 + vkh;
      for (int i = 0; i < 4; ++i) kpre[i] = *(const short8*)(kg + i * 8);
      for (int i = 0; i < 4; ++i) vpre[i] = *(const short8*)(vg + i * 8);
    }
    wg_barrier();

    // S = Q K^T (Q pre-scaled so S is already log2-domain); K-frags read once, shared by both mi
    f32x4 sf[2][8];
    for (int nk = 0; nk < 8; ++nk) {
      short8 bk0 = *(const short8*)&Ks[(nk * 16 + col) * 72 + quad * 8];
      short8 bk1 = *(const short8*)&Ks[(nk * 16 + col) * 72 + 32 + quad * 8];
      f32x4 z0 = fzero4(), z1 = fzero4();
      z0 = __builtin_amdgcn_mfma_f32_16x16x32_bf16(aq[0][0], bk0, z0, 0, 0, 0);
      z0 = __builtin_amdgcn_mfma_f32_16x16x32_bf16(aq[0][1], bk1, z0, 0, 0, 0);
      z1 = __builtin_amdgcn_mfma_f32_16x16x32_bf16(aq[1][0], bk0, z1, 0, 0, 0);
      z1 = __builtin_amdgcn_mfma_f32_16x16x32_bf16(aq[1][1], bk1, z1, 0, 0, 0);
      sf[0][nk] = z0;
      sf[1][nk] = z1;
    }

    // p = 2^s (no max-sub: scores bounded, shift-invariant); pack f16 pairs, write P
    for (int mi = 0; mi < 2; ++mi)
      for (int nk = 0; nk < 8; ++nk)
        for (int r = 0; r < 4; ++r)
          sf[mi][nk][r] = __builtin_amdgcn_exp2f(sf[mi][nk][r]);
    for (int mi = 0; mi < 2; ++mi)
      for (int r = 0; r < 4; ++r) {
        int row = qbase + mi * 16 + quad * 4 + r;
        uint2 d0, d1;
        d0.x = pkh2(sf[mi][0][r], sf[mi][1][r]);
        d0.y = pkh2(sf[mi][2][r], sf[mi][3][r]);
        d1.x = pkh2(sf[mi][4][r], sf[mi][5][r]);
        d1.y = pkh2(sf[mi][6][r], sf[mi][7][r]);
        *(uint2*)&Ps[row * 136 + col * 4]      = d0;
        *(uint2*)&Ps[row * 136 + 64 + col * 4] = d1;
      }
    // no barrier: each wave reads only its own Ps rows

    // O += P V (f16); ni=4 tile hits the ones-row -> oa[mi][4] lane col0 = row-sum
    for (int ks = 0; ks < 4; ++ks) {
      int koff = ks * 32 + quad * 8;
      half8 ap0 = *(const half8*)&Ps[(qbase + col) * 136 + koff];
      half8 ap1 = *(const half8*)&Ps[(qbase + 16 + col) * 136 + koff];
      for (int ni = 0; ni < 5; ++ni) {
        half8 bv = *(const half8*)&Vs[(ni * 16 + col) * 136 + koff];
        oa[0][ni] = __builtin_amdgcn_mfma_f32_16x16x32_f16(ap0, bv, oa[0][ni], 0, 0, 0);
        oa[1][ni] = __builtin_amdgcn_mfma_f32_16x16x32_f16(ap1, bv, oa[1][ni], 0, 0, 0);
      }
    }
  }

  // normalize: lsum lives in oa[mi][4][r] of each quad's col-0 lane; broadcast within quad
  float inv[2][4];
  for (int mi = 0; mi < 2; ++mi)
    for (int r = 0; r < 4; ++r) {
      float s = __shfl(oa[mi][4][r], lane & 48);
      inv[mi][r] = 1.f / s;
    }
  __syncthreads();
  for (int mi = 0; mi < 2; ++mi)
    for (int ni = 0; ni < 4; ++ni)
      for (int r = 0; r < 4; ++r)
        Ps[(qbase + mi * 16 + quad * 4 + r) * 64 + ni * 16 + col] = f2bf(oa[mi][ni][r] * inv[mi][r]);
  __syncthreads();
  for (int it = 0; it < 4; ++it) {
    int f = (it * 256 + tid) * 8;  // over [128 q][64 d]
    int q = f >> 6, d = f & 63;
    short8 val = *(const short8*)&Ps[q * 64 + d];
    *(short8*)(O + ((size_t)(b * 1024 + qt * 128 + q)) * 1024 + h * 64 + d) = val;
  }
}

// ---------- launcher ----------
extern "C" void kernel_launch(void* const* d_in, const int* in_sizes, int n_in,
                              void* d_out, int out_size, void* d_ws, size_t ws_size,
                              hipStream_t stream) {
  const float* x1 = (const float*)d_in[0];
  const float* x2 = (const float*)d_in[1];
  const float* Wq = (const float*)d_in[2];
  const float* bq = (const float*)d_in[3];
  const float* Wk = (const float*)d_in[4];
  const float* bk = (const float*)d_in[5];
  const float* Wv = (const float*)d_in[6];
  const float* bv = (const float*)d_in[7];
  const float* Wo = (const float*)d_in[8];
  const float* bo = (const float*)d_in[9];

  char* ws = (char*)d_ws;
  short* xb1 = (short*)(ws + 0);         // x1 bf16, 8 MB
  short* xb2 = (short*)(ws + 8388608);   // x2 bf16, 16 MB
  short* wqb = (short*)(ws + 25165824);  // Wq bf16, 2 MB
  short* wkb = (short*)(ws + 27262976);
  short* wvb = (short*)(ws + 29360128);
  short* wob = (short*)(ws + 31457280);
  short* qb  = (short*)(ws + 33554432);  // q [bh][1024][64] bf16 (pre-scaled), 8 MB
  short* kb  = (short*)(ws + 41943040);  // k [bh][2048][64] bf16, 16 MB
  short* vb  = (short*)(ws + 58720256);  // v tiled f16 [bh][32][64][64], 16 MB
  short* ob  = (short*)(ws + 75497472);  // attn out [4096][1024] bf16, 8 MB

  cvt_all<<<16384, 256, 0, stream>>>(x1, x2, Wq, Wk, Wv, Wo, (short*)ws);
  proj<<<dim3(160, 8), 256, 0, stream>>>(xb1, xb2, wqb, wkb, wvb, bq, bk, bv, qb, kb, vb);
  attn<<<dim3(64, 8), 256, 0, stream>>>(qb, kb, vb, ob);
  out_gemm<<<dim3(16, 32), 256, 0, stream>>>(ob, wob, bo, (float*)d_out);
}

// Round 9
// 235.027 us; speedup vs baseline: 1.0155x; 1.0004x over previous
//
#include <hip/hip_runtime.h>

typedef __attribute__((ext_vector_type(8))) short short8;
typedef __attribute__((ext_vector_type(4))) short short4v;
typedef __attribute__((ext_vector_type(4))) float f32x4;
typedef _Float16 half8 __attribute__((ext_vector_type(8)));

#define ASYNC16(g, l) __builtin_amdgcn_global_load_lds( \
    (__attribute__((address_space(1))) void*)(g), \
    (__attribute__((address_space(3))) void*)(l), 16, 0, 0)

__device__ __forceinline__ short f2bf(float f) {
  union { float f; unsigned u; } v; v.f = f;
  unsigned r = v.u + 0x7fffu + ((v.u >> 16) & 1u);
  return (short)(r >> 16);
}

__device__ __forceinline__ short f2h(float f) {  // f32 -> f16 bits (RTNE)
  _Float16 h = (_Float16)f;
  return __builtin_bit_cast(short, h);
}

__device__ __forceinline__ unsigned pkh2(float a, float b) {  // 2xf16 packed, RTZ
  return __builtin_bit_cast(unsigned, __builtin_amdgcn_cvt_pkrtz(a, b));
}

__device__ __forceinline__ f32x4 fzero4() {
  f32x4 z; z[0] = 0.f; z[1] = 0.f; z[2] = 0.f; z[3] = 0.f; return z;
}

// barrier that does NOT drain vmcnt: in-flight DMA stages / reg prefetches survive.
__device__ __forceinline__ void wg_barrier() {
  asm volatile("s_waitcnt lgkmcnt(0)\n\ts_barrier" ::: "memory");
}

// counted waits (T4): oldest loads landed + all waves synced. Never vmcnt(0) mid-loop.
__device__ __forceinline__ void wait4_barrier() {
  asm volatile("s_waitcnt vmcnt(4) lgkmcnt(0)\n\ts_barrier" ::: "memory");
}
__device__ __forceinline__ void wait6_barrier() {
  asm volatile("s_waitcnt vmcnt(6)\n\ts_barrier" ::: "memory");
}
__device__ __forceinline__ void wait0_barrier() {
  asm volatile("s_waitcnt vmcnt(0)\n\ts_barrier" ::: "memory");
}

// ---------- fp32 -> bf16 conversion of x1, x2, Wq, Wk, Wv, Wo ----------
__global__ __launch_bounds__(256) void cvt_all(
    const float* __restrict__ x1, const float* __restrict__ x2,
    const float* __restrict__ wq, const float* __restrict__ wk,
    const float* __restrict__ wv, const float* __restrict__ wo,
    short* __restrict__ dst) {
  long e = ((long)blockIdx.x * 256 + threadIdx.x) * 4;
  const float* src; long loc;
  if (e < 4194304L)       { src = x1; loc = e; }
  else if (e < 12582912L) { src = x2; loc = e - 4194304L; }
  else if (e < 13631488L) { src = wq; loc = e - 12582912L; }
  else if (e < 14680064L) { src = wk; loc = e - 13631488L; }
  else if (e < 15728640L) { src = wv; loc = e - 14680064L; }
  else                    { src = wo; loc = e - 15728640L; }
  float4 v = *(const float4*)(src + loc);
  short4v o;
  o[0] = f2bf(v.x); o[1] = f2bf(v.y); o[2] = f2bf(v.z); o[3] = f2bf(v.w);
  *(short4v*)(dst + e) = o;
}

// ---------- fused Q/K/V projection GEMM ----------
// FROZEN (R8): 3-buffer counted pipeline + bank-swizzle + unroll-by-3.
// 64-68 us across 7 structural variants; within ~1.35x of the 128^2-structure
// ceiling (43 GFLOP @ ~900 TF = 48 us + epilogue). Do not touch.
__global__ __launch_bounds__(256) void proj(
    const short* __restrict__ xb1, const short* __restrict__ xb2,
    const short* __restrict__ wqp, const short* __restrict__ wkp, const short* __restrict__ wvp,
    const float* __restrict__ bq, const float* __restrict__ bk, const float* __restrict__ bv,
    short* __restrict__ qb, short* __restrict__ kb, short* __restrict__ vb) {
  __shared__ short smem[24576];  // 3 bufs x 8192 shorts (A:4096 | B:4096)
  const int tid = threadIdx.x, w = tid >> 6, lane = tid & 63;
  const int quad = lane >> 4, col = lane & 15;
  const int waveM = (w >> 1) * 64, waveN = (w & 1) * 64;
  const int my = blockIdx.x, bn = blockIdx.y * 128;
  const short* A; const short* W; const float* bias; int mode, bm;
  if (my < 32)      { A = xb1; W = wqp; bias = bq; mode = 0; bm = my * 128; }
  else if (my < 96) { A = xb2; W = wkp; bias = bk; mode = 1; bm = (my - 32) * 128; }
  else              { A = xb2; W = wvp; bias = bv; mode = 2; bm = (my - 96) * 128; }

  f32x4 acc[4][4];
  for (int mi = 0; mi < 4; ++mi)
    for (int ni = 0; ni < 4; ++ni)
      acc[mi][ni] = fzero4();

  // staging: lane l fills LDS slot (row = l>>2, chunk = l&3); under the swizzle that
  // slot holds logical chunk (l&3)^((l>>3)&3)  [bits 1-2 of row = (l>>3)&3].
  const int srow = w * 16 + (lane >> 2);
  const int scol = ((lane & 3) ^ ((lane >> 3) & 3)) * 8;
  const short* ga = A + (size_t)(bm + srow) * 1024 + scol;
  const short* gb = W + (size_t)(bn + srow) * 1024 + scol;
  // read-side swizzle: fragment row bits 1-2 = col bits 1-2 (waveM/mi*16 are mult of 16)
  const int csw = (col >> 1) & 3;

  // hoisted fragment offsets (loop-invariant)
  int aoff[4], boff[4];
  for (int mi = 0; mi < 4; ++mi)
    aoff[mi] = (waveM + mi * 16 + col) * 32 + (quad ^ csw) * 8;
  for (int ni = 0; ni < 4; ++ni)
    boff[ni] = 4096 + (waveN + ni * 16 + col) * 32 + (quad ^ csw) * 8;
  short* const stA = smem + w * 512;
  short* const stB = smem + 4096 + w * 512;

#define PSTAGE(B, KK) do {                       \
    ASYNC16(ga + (KK),         stA + (B) * 8192); \
    ASYNC16(ga + (KK) + 65536, stA + (B) * 8192 + 2048); \
    ASYNC16(gb + (KK),         stB + (B) * 8192); \
    ASYNC16(gb + (KK) + 65536, stB + (B) * 8192 + 2048); \
  } while (0)

#define PCOMPUTE(B, KK) do {                     \
    const short* base_ = smem + (B) * 8192;      \
    short8 af[4], bf[4];                         \
    for (int mi = 0; mi < 4; ++mi)               \
      af[mi] = *(const short8*)(base_ + aoff[mi]); \
    for (int ni = 0; ni < 4; ++ni)               \
      bf[ni] = *(const short8*)(base_ + boff[ni]); \
    for (int mi = 0; mi < 4; ++mi)               \
      for (int ni = 0; ni < 4; ++ni)             \
        acc[mi][ni] = __builtin_amdgcn_mfma_f32_16x16x32_bf16(af[mi], bf[ni], acc[mi][ni], 0, 0, 0); \
  } while (0)

  // prologue: K-tiles 0,1 in flight (8 loads)
  PSTAGE(0, 0);
  PSTAGE(1, 32);
  // main: 10 macro-iters x 3 kt (all buffer indices literal), kt=30,31 peeled
#pragma unroll 1
  for (int t = 0; t < 10; ++t) {
    const int kk = t * 96;
    wait4_barrier(); PSTAGE(2, kk + 64);  PCOMPUTE(0, kk);
    wait4_barrier(); PSTAGE(0, kk + 96);  PCOMPUTE(1, kk + 32);
    wait4_barrier(); PSTAGE(1, kk + 128); PCOMPUTE(2, kk + 64);
  }
  wait4_barrier();  PCOMPUTE(0, 960);   // kt=30 (no stage: kt+2 would be 32)
  wait0_barrier();  PCOMPUTE(1, 992);   // kt=31
  __syncthreads();                      // all reads done before epilogue overwrites
#undef PSTAGE
#undef PCOMPUTE

  for (int ni = 0; ni < 4; ++ni) {
    int nn = waveN + ni * 16 + col;
    float bvl = bias[bn + nn];
    for (int mi = 0; mi < 4; ++mi) {
      int m0 = waveM + mi * 16 + quad * 4;
      for (int r = 0; r < 4; ++r) {
        int m = m0 + r;
        float val = acc[mi][ni][r] + bvl;
        short sv;
        if (mode == 0)      sv = f2bf(val * 0.18033688011112042f);  // log2(e)/8
        else if (mode == 1) sv = f2bf(val);
        else                sv = f2h(val);                           // V in f16
        smem[m * 128 + (nn ^ ((m & 15) << 3))] = sv;
      }
    }
  }
  __syncthreads();
  if (mode < 2) {
    const int S = (mode == 0) ? 1024 : 2048;
    short* outp = (mode == 0) ? qb : kb;
    const int bb = bm / S, s0 = bm & (S - 1), h0 = bn >> 6;
    for (int it = 0; it < 8; ++it) {
      int f = (it * 256 + tid) * 8;
      int hh = f >> 13, rem = f & 8191, m = rem >> 6, d = rem & 63;
      int nn = hh * 64 + d;
      short8 val = *(const short8*)&smem[m * 128 + (nn ^ ((m & 15) << 3))];
      *(short8*)(outp + ((((size_t)(bb * 16 + h0 + hh)) * S + s0 + m) * 64 + d)) = val;
    }
  } else {
    // v tiled transposed f16: [bh][kt64][d][kv'], kv' = (kv%16)*4 + kv/16
    const int bb = bm >> 11, s0 = bm & 2047, kt0 = s0 >> 6, h0 = bn >> 6;
    for (int it = 0; it < 8; ++it) {
      int f = (it * 256 + tid) * 8;
      int hh = f >> 13, rem = f & 8191, ktl = rem >> 12, r3 = rem & 4095;
      int d = r3 >> 6, kvp0 = r3 & 63;
      int nn = hh * 64 + d;
      short8 val;
      for (int j = 0; j < 8; ++j) {
        int kvp = kvp0 + j;
        int kv = ((kvp & 3) << 4) | (kvp >> 2);
        int m = ktl * 64 + kv;
        val[j] = smem[m * 128 + (nn ^ ((m & 15) << 3))];
      }
      *(short8*)(vb + ((((size_t)(bb * 16 + h0 + hh)) * 32 + (kt0 + ktl)) * 4096) + d * 64 + kvp0) = val;
    }
  }
}

// ---------- output GEMM: out[4096,1024] fp32 = ob @ Wo^T + bo ----------
// 128x64 tiles, BK=64, grid (16 n, 32 m) = 512 blocks.
// R2's 2-deep counted-vmcnt pipeline (proven win) — unchanged.
__global__ __launch_bounds__(256) void out_gemm(
    const short* __restrict__ A, const short* __restrict__ W,
    const float* __restrict__ bias, float* __restrict__ out) {
  __shared__ short smem[24576];  // buf b at b*12288: A0 | A1 (4096 each) | B0 | B1 (2048 each)
  const int tid = threadIdx.x, w = tid >> 6, lane = tid & 63;
  const int quad = lane >> 4, col = lane & 15;
  const int waveM = (w >> 1) * 64, waveN = (w & 1) * 32;
  const int bn = blockIdx.x * 64, bm = blockIdx.y * 128;

  f32x4 acc[4][2];
  for (int mi = 0; mi < 4; ++mi)
    for (int ni = 0; ni < 2; ++ni)
      acc[mi][ni] = fzero4();

  const int arow = w * 16 + (lane >> 2), ac = (lane & 3) * 8;
  const short* ga = A + (size_t)(bm + arow) * 1024 + ac;
  const short* gb = W + (size_t)(bn + (tid >> 2)) * 1024 + (tid & 3) * 8;

  auto stage = [&](int b, int kk) {
    short* base = smem + b * 12288;
    short* lA0 = base + w * 512;
    short* lA1 = base + 4096 + w * 512;
    short* lB0 = base + 8192 + w * 512;
    short* lB1 = base + 10240 + w * 512;
    ASYNC16(ga + kk,              lA0);
    ASYNC16(ga + kk + 65536,      lA0 + 2048);
    ASYNC16(ga + kk + 32,         lA1);
    ASYNC16(ga + kk + 32 + 65536, lA1 + 2048);
    ASYNC16(gb + kk,              lB0);
    ASYNC16(gb + kk + 32,         lB1);
  };
  auto compute = [&](int b) {
    const short* base = smem + b * 12288;
    for (int kh = 0; kh < 2; ++kh) {
      const short* Ash = base + kh * 4096;
      const short* Bsh = base + 8192 + kh * 2048;
      short8 af[4], bf[2];
      for (int mi = 0; mi < 4; ++mi)
        af[mi] = *(const short8*)(Ash + (waveM + mi * 16 + col) * 32 + quad * 8);
      for (int ni = 0; ni < 2; ++ni)
        bf[ni] = *(const short8*)(Bsh + (waveN + ni * 16 + col) * 32 + quad * 8);
      for (int mi = 0; mi < 4; ++mi)
        for (int ni = 0; ni < 2; ++ni)
          acc[mi][ni] = __builtin_amdgcn_mfma_f32_16x16x32_bf16(af[mi], bf[ni], acc[mi][ni], 0, 0, 0);
    }
  };

  // prologue: tiles 0,1 in flight (12 loads)
  stage(0, 0);
  stage(1, 64);
  for (int it = 0; it < 14; ++it) {
    wait6_barrier();               // tile it landed (oldest 6 of 12)
    compute(it & 1);
    wg_barrier();                  // reads retired -> safe to re-stage
    stage(it & 1, (it + 2) * 64);
  }
  wait6_barrier();                 // tile 14 landed
  compute(0);
  wait0_barrier();                 // tile 15 landed
  compute(1);

  for (int ni = 0; ni < 2; ++ni) {
    int n = bn + waveN + ni * 16 + col;
    float bvl = bias[n];
    for (int mi = 0; mi < 4; ++mi) {
      int m0 = bm + waveM + mi * 16 + quad * 4;
      for (int r = 0; r < 4; ++r)
        out[(size_t)(m0 + r) * 1024 + n] = acc[mi][ni][r] + bvl;
    }
  }
}

// ---------- flash attention: KVBLK=64 for 4 blocks/CU ----------
// Was KVBLK=128 with 75KB LDS -> 2 blocks/CU -> 2 waves/SIMD: the serial
// QK^T -> exp2/pack (VALU) -> PV chain had nothing to co-schedule against.
// Now Ks[64x72]+Vs[80x72]+Ps[128x72] = 39.2KB -> 4 blocks/CU -> 4 waves/SIMD.
// Same per-kv math; kv'-permutation of vb is per-64-chunk so P-pack <-> V-layout
// k-slot alignment is preserved; ones-row/normalize/epilogue unchanged.
__global__ __launch_bounds__(256, 4) void attn(
    const short* __restrict__ Q, const short* __restrict__ K,
    const short* __restrict__ V, short* __restrict__ O) {
  __shared__ short Ks[64 * 72];
  __shared__ short Vs[80 * 72];    // f16 [d][kv']; rows 64..79: ones row + zeros (lsum)
  __shared__ short Ps[128 * 72];   // f16 [q][kv' packed]
  const int tid = threadIdx.x, w = tid >> 6, lane = tid & 63;
  const int quad = lane >> 4, col = lane & 15;
  const int bh = blockIdx.x, qt = blockIdx.y;
  const int b = bh >> 4, h = bh & 15;
  const int qbase = w * 32;

  const short* qp = Q + ((size_t)bh * 1024 + qt * 128) * 64;
  const short* kp = K + (size_t)bh * 131072;
  const short* vp = V + (size_t)bh * 131072;

  short8 aq[2][2];
  for (int mi = 0; mi < 2; ++mi) {
    const short* qr = qp + (qbase + mi * 16 + col) * 64 + quad * 8;
    aq[mi][0] = *(const short8*)qr;
    aq[mi][1] = *(const short8*)(qr + 32);
  }

  f32x4 oa[2][5];
  for (int mi = 0; mi < 2; ++mi)
    for (int ni = 0; ni < 5; ++ni)
      oa[mi][ni] = fzero4();

  // ones row (f16 1.0 = 0x3C00) at d=64; zeros d=65..79 (stride 72)
  for (int i = tid; i < 16 * 72; i += 256)
    Vs[64 * 72 + i] = (i < 72) ? (short)0x3C00 : (short)0;

  // cooperative 64x64 tile loads: K by (row, 16-col chunk); V by (d=lane, kv' 16-chunk)
  const int krow = w * 16 + (lane >> 2), kcol = (lane & 3) * 16;
  const int vd = lane, vkc = w * 16;

  short8 kpre[2], vpre[2];
  {
    const short* kg = kp + krow * 64 + kcol;
    const short* vg = vp + vd * 64 + vkc;
    kpre[0] = *(const short8*)kg;
    kpre[1] = *(const short8*)(kg + 8);
    vpre[0] = *(const short8*)vg;
    vpre[1] = *(const short8*)(vg + 8);
  }

  for (int kt = 0; kt < 32; ++kt) {
    wg_barrier();  // prior tile's LDS reads done (lgkm only; prefetch vmcnt in flight)
    *(short8*)&Ks[krow * 72 + kcol]     = kpre[0];
    *(short8*)&Ks[krow * 72 + kcol + 8] = kpre[1];
    *(short8*)&Vs[vd * 72 + vkc]        = vpre[0];
    *(short8*)&Vs[vd * 72 + vkc + 8]    = vpre[1];
    {
      int ktn = (kt < 31) ? kt + 1 : kt;
      const short* kg = kp + ktn * 4096 + krow * 64 + kcol;
      const short* vg = vp + ktn * 4096 + vd * 64 + vkc;
      kpre[0] = *(const short8*)kg;
      kpre[1] = *(const short8*)(kg + 8);
      vpre[0] = *(const short8*)vg;
      vpre[1] = *(const short8*)(vg + 8);
    }
    wg_barrier();

    // S = Q K^T (Q pre-scaled so S is already log2-domain)
    f32x4 sf[2][4];
    for (int nk = 0; nk < 4; ++nk) {
      short8 bk0 = *(const short8*)&Ks[(nk * 16 + col) * 72 + quad * 8];
      short8 bk1 = *(const short8*)&Ks[(nk * 16 + col) * 72 + 32 + quad * 8];
      f32x4 z0 = fzero4(), z1 = fzero4();
      z0 = __builtin_amdgcn_mfma_f32_16x16x32_bf16(aq[0][0], bk0, z0, 0, 0, 0);
      z0 = __builtin_amdgcn_mfma_f32_16x16x32_bf16(aq[0][1], bk1, z0, 0, 0, 0);
      z1 = __builtin_amdgcn_mfma_f32_16x16x32_bf16(aq[1][0], bk0, z1, 0, 0, 0);
      z1 = __builtin_amdgcn_mfma_f32_16x16x32_bf16(aq[1][1], bk1, z1, 0, 0, 0);
      sf[0][nk] = z0;
      sf[1][nk] = z1;
    }

    // p = 2^s; pack f16 pairs into Ps (position p = col*4+nk <-> kv = nk*16+col,
    // matching vb's kv' permutation)
    for (int mi = 0; mi < 2; ++mi)
      for (int nk = 0; nk < 4; ++nk)
        for (int r = 0; r < 4; ++r)
          sf[mi][nk][r] = __builtin_amdgcn_exp2f(sf[mi][nk][r]);
    for (int mi = 0; mi < 2; ++mi)
      for (int r = 0; r < 4; ++r) {
        int row = qbase + mi * 16 + quad * 4 + r;
        uint2 d0;
        d0.x = pkh2(sf[mi][0][r], sf[mi][1][r]);
        d0.y = pkh2(sf[mi][2][r], sf[mi][3][r]);
        *(uint2*)&Ps[row * 72 + col * 4] = d0;
      }
    // no barrier: each wave reads only its own Ps rows

    // O += P V (f16); ni=4 hits the ones-row -> oa[mi][4] quad-col0 = row-sum
    for (int ks = 0; ks < 2; ++ks) {
      int koff = ks * 32 + quad * 8;
      half8 ap0 = *(const half8*)&Ps[(qbase + col) * 72 + koff];
      half8 ap1 = *(const half8*)&Ps[(qbase + 16 + col) * 72 + koff];
      for (int ni = 0; ni < 5; ++ni) {
        half8 bv = *(const half8*)&Vs[(ni * 16 + col) * 72 + koff];
        oa[0][ni] = __builtin_amdgcn_mfma_f32_16x16x32_f16(ap0, bv, oa[0][ni], 0, 0, 0);
        oa[1][ni] = __builtin_amdgcn_mfma_f32_16x16x32_f16(ap1, bv, oa[1][ni], 0, 0, 0);
      }
    }
  }

  // normalize: lsum lives in oa[mi][4][r] of each quad's col-0 lane; broadcast within quad
  float inv[2][4];
  for (int mi = 0; mi < 2; ++mi)
    for (int r = 0; r < 4; ++r) {
      float s = __shfl(oa[mi][4][r], lane & 48);
      inv[mi][r] = 1.f / s;
    }
  __syncthreads();
  for (int mi = 0; mi < 2; ++mi)
    for (int ni = 0; ni < 4; ++ni)
      for (int r = 0; r < 4; ++r)
        Ps[(qbase + mi * 16 + quad * 4 + r) * 64 + ni * 16 + col] = f2bf(oa[mi][ni][r] * inv[mi][r]);
  __syncthreads();
  for (int it = 0; it < 4; ++it) {
    int f = (it * 256 + tid) * 8;  // over [128 q][64 d]
    int q = f >> 6, d = f & 63;
    short8 val = *(const short8*)&Ps[q * 64 + d];
    *(short8*)(O + ((size_t)(b * 1024 + qt * 128 + q)) * 1024 + h * 64 + d) = val;
  }
}

// ---------- launcher ----------
extern "C" void kernel_launch(void* const* d_in, const int* in_sizes, int n_in,
                              void* d_out, int out_size, void* d_ws, size_t ws_size,
                              hipStream_t stream) {
  const float* x1 = (const float*)d_in[0];
  const float* x2 = (const float*)d_in[1];
  const float* Wq = (const float*)d_in[2];
  const float* bq = (const float*)d_in[3];
  const float* Wk = (const float*)d_in[4];
  const float* bk = (const float*)d_in[5];
  const float* Wv = (const float*)d_in[6];
  const float* bv = (const float*)d_in[7];
  const float* Wo = (const float*)d_in[8];
  const float* bo = (const float*)d_in[9];

  char* ws = (char*)d_ws;
  short* xb1 = (short*)(ws + 0);         // x1 bf16, 8 MB
  short* xb2 = (short*)(ws + 8388608);   // x2 bf16, 16 MB
  short* wqb = (short*)(ws + 25165824);  // Wq bf16, 2 MB
  short* wkb = (short*)(ws + 27262976);
  short* wvb = (short*)(ws + 29360128);
  short* wob = (short*)(ws + 31457280);
  short* qb  = (short*)(ws + 33554432);  // q [bh][1024][64] bf16 (pre-scaled), 8 MB
  short* kb  = (short*)(ws + 41943040);  // k [bh][2048][64] bf16, 16 MB
  short* vb  = (short*)(ws + 58720256);  // v tiled f16 [bh][32][64][64], 16 MB
  short* ob  = (short*)(ws + 75497472);  // attn out [4096][1024] bf16, 8 MB

  cvt_all<<<16384, 256, 0, stream>>>(x1, x2, Wq, Wk, Wv, Wo, (short*)ws);
  proj<<<dim3(160, 8), 256, 0, stream>>>(xb1, xb2, wqb, wkb, wvb, bq, bk, bv, qb, kb, vb);
  attn<<<dim3(64, 8), 256, 0, stream>>>(qb, kb, vb, ob);
  out_gemm<<<dim3(16, 32), 256, 0, stream>>>(ob, wob, bo, (float*)d_out);
}